// Round 2
// baseline (694.142 us; speedup 1.0000x reference)
//
#include <hip/hip_runtime.h>
#include <hip/hip_bf16.h>

#define N_NODES 100000
#define N_EDGES 1600000
#define IN_F 128
#define C1 64      // HEADS*HID
#define NC 16      // classes / layer2 width

__device__ __forceinline__ float lrelu(float x) { return fmaxf(x, 0.2f * x); }

// ---------------- CSR build ----------------
__global__ void k_hist(const int* __restrict__ dst, int* __restrict__ deg) {
    int e = blockIdx.x * 256 + threadIdx.x;          // grid exactly E/256
    atomicAdd(&deg[dst[e]], 1);
}

__global__ void k_scan(const int* __restrict__ deg, int* __restrict__ rowptr) {
    __shared__ int buf[1024];
    int tid = threadIdx.x;
    int offset = 0;
    for (int base = 0; base < N_NODES; base += 1024) {
        int i = base + tid;
        int v = (i < N_NODES) ? deg[i] : 0;
        buf[tid] = v;
        __syncthreads();
        for (int d = 1; d < 1024; d <<= 1) {
            int t = (tid >= d) ? buf[tid - d] : 0;
            __syncthreads();
            buf[tid] += t;
            __syncthreads();
        }
        if (i < N_NODES) rowptr[i] = offset + buf[tid] - v;   // exclusive
        offset += buf[1023];
        __syncthreads();
    }
    if (tid == 0) rowptr[N_NODES] = offset;   // == E
}

__global__ void k_scatter(const int* __restrict__ src, const int* __restrict__ dst,
                          const int* __restrict__ rowptr, int* __restrict__ cnt,
                          int* __restrict__ csr_src) {
    int e = blockIdx.x * 256 + threadIdx.x;
    int d = dst[e];
    int k = atomicAdd(&cnt[d], 1);
    csr_src[rowptr[d] + k] = src[e];
}

// ---------------- layer 1 GEMM + attention dots ----------------
// 16 nodes per 256-thread block; thread t: node_l = t>>4, cols (t&15)*4 .. +3
__global__ __launch_bounds__(256) void k_gemm1(
    const float* __restrict__ x, const float* __restrict__ W1,
    const float* __restrict__ att_src1, const float* __restrict__ att_dst1,
    float* __restrict__ h1, float* __restrict__ a_src1, float* __restrict__ a_dst1) {
    __shared__ __align__(16) float wS[IN_F * C1];   // 32 KB, [k][col]
    __shared__ __align__(16) float xS[16 * 132];    // stride 132: aligned + conflict-free
    __shared__ float aSs[C1], aSd[C1];
    int tid = threadIdx.x;
    int node0 = blockIdx.x * 16;
    for (int i = tid; i < (IN_F * C1) / 4; i += 256)
        *(float4*)&wS[i * 4] = *(const float4*)&W1[i * 4];
    for (int i = tid; i < (16 * IN_F) / 4; i += 256) {
        int r = i >> 5, c4 = (i & 31) << 2;          // 32 float4 per 128-wide row
        *(float4*)&xS[r * 132 + c4] = *(const float4*)&x[(node0 + r) * IN_F + c4];
    }
    if (tid < C1) { aSs[tid] = att_src1[tid]; aSd[tid] = att_dst1[tid]; }
    __syncthreads();

    int node_l = tid >> 4;
    int cq = (tid & 15) << 2;
    const float* xrow = &xS[node_l * 132];
    float4 acc = {0.f, 0.f, 0.f, 0.f};
#pragma unroll 4
    for (int k = 0; k < IN_F; k++) {
        float xv = xrow[k];
        float4 wv = *(const float4*)&wS[k * C1 + cq];
        acc.x += xv * wv.x; acc.y += xv * wv.y; acc.z += xv * wv.z; acc.w += xv * wv.w;
    }
    int node = node0 + node_l;
    *(float4*)&h1[node * C1 + cq] = acc;

    float ps = acc.x * aSs[cq] + acc.y * aSs[cq + 1] + acc.z * aSs[cq + 2] + acc.w * aSs[cq + 3];
    float pd = acc.x * aSd[cq] + acc.y * aSd[cq + 1] + acc.z * aSd[cq + 2] + acc.w * aSd[cq + 3];
    ps += __shfl_xor(ps, 1); ps += __shfl_xor(ps, 2);
    pd += __shfl_xor(pd, 1); pd += __shfl_xor(pd, 2);
    if ((tid & 3) == 0) {
        int h = (tid & 15) >> 2;
        a_src1[node * 4 + h] = ps;
        a_dst1[node * 4 + h] = pd;
    }
}

// ---------------- layer 1 segment-softmax + aggregate (one wave per node) ----
__global__ __launch_bounds__(256) void k_agg1(
    const float* __restrict__ h1, const float* __restrict__ a_src1,
    const float* __restrict__ a_dst1, const int* __restrict__ rowptr,
    const int* __restrict__ csr_src, const float* __restrict__ b1,
    float* __restrict__ out_emb) {
    int lane = threadIdx.x & 63;
    int node = blockIdx.x * 4 + (threadIdx.x >> 6);
    int col = lane, h = lane >> 4;
    int rs = rowptr[node];
    int deg = rowptr[node + 1] - rs;

    float4 ad4 = *(const float4*)&a_dst1[node * 4];
    float4 as4 = *(const float4*)&a_src1[node * 4];
    float e0x = lrelu(as4.x + ad4.x), e0y = lrelu(as4.y + ad4.y);
    float e0z = lrelu(as4.z + ad4.z), e0w = lrelu(as4.w + ad4.w);
    float mx = e0x, my = e0y, mz = e0z, mw = e0w;   // self-loop seeds the max

    for (int base = 0; base < deg; base += 64) {    // pass 1: lane-parallel max
        int idx = base + lane;
        if (idx < deg) {
            int s = csr_src[rs + idx];
            float4 as = *(const float4*)&a_src1[s * 4];
            mx = fmaxf(mx, lrelu(as.x + ad4.x));
            my = fmaxf(my, lrelu(as.y + ad4.y));
            mz = fmaxf(mz, lrelu(as.z + ad4.z));
            mw = fmaxf(mw, lrelu(as.w + ad4.w));
        }
    }
    for (int off = 32; off; off >>= 1) {
        mx = fmaxf(mx, __shfl_xor(mx, off));
        my = fmaxf(my, __shfl_xor(my, off));
        mz = fmaxf(mz, __shfl_xor(mz, off));
        mw = fmaxf(mw, __shfl_xor(mw, off));
    }
    float m_h  = (h == 0) ? mx : (h == 1) ? my : (h == 2) ? mz : mw;
    float e0_h = (h == 0) ? e0x : (h == 1) ? e0y : (h == 2) ? e0z : e0w;

    float w0 = __expf(e0_h - m_h);                  // self-loop contribution
    float sacc = w0;
    float acc  = w0 * h1[node * C1 + col];

    for (int base = 0; base < deg; base += 64) {    // pass 2: lane-per-column gather
        int idx = base + lane;
        int s_l = 0;
        float4 w4 = {0.f, 0.f, 0.f, 0.f};
        if (idx < deg) {                            // lane-parallel weight precompute
            s_l = csr_src[rs + idx];
            float4 as = *(const float4*)&a_src1[s_l * 4];
            w4.x = __expf(lrelu(as.x + ad4.x) - mx);
            w4.y = __expf(lrelu(as.y + ad4.y) - my);
            w4.z = __expf(lrelu(as.z + ad4.z) - mz);
            w4.w = __expf(lrelu(as.w + ad4.w) - mw);
        }
        int nrem = min(64, deg - base);
        for (int j = 0; j < nrem; j++) {
            int s = __shfl(s_l, j);
            float wx = __shfl(w4.x, j), wy = __shfl(w4.y, j);
            float wz = __shfl(w4.z, j), ww = __shfl(w4.w, j);
            float wj = (h == 0) ? wx : (h == 1) ? wy : (h == 2) ? wz : ww;
            sacc += wj;
            acc += wj * h1[s * C1 + col];
        }
    }
    float o = acc / sacc + b1[col];
    o = (o > 0.f) ? o : expm1f(o);                  // ELU
    out_emb[node * C1 + col] = o;                   // fp32 embeddings == h_act
}

// ---------------- layer 2 GEMM + attention dots ----------------
__global__ __launch_bounds__(256) void k_gemm2(
    const float* __restrict__ h_act, const float* __restrict__ W2,
    const float* __restrict__ att_src2, const float* __restrict__ att_dst2,
    float* __restrict__ h2, float* __restrict__ a_src2, float* __restrict__ a_dst2) {
    __shared__ float wS[C1 * NC];                 // 4 KB [k][c]
    __shared__ __align__(16) float hS[16 * 68];   // stride 68: aligned + conflict-free
    __shared__ float aS[NC], aD[NC];
    int tid = threadIdx.x;
    int node0 = blockIdx.x * 16;
    if (tid < (C1 * NC) / 4)
        *(float4*)&wS[tid * 4] = *(const float4*)&W2[tid * 4];
    {   // 16 rows x 64 cols of h_act, 256 float4s
        int r = tid >> 4, c4 = (tid & 15) << 2;
        *(float4*)&hS[r * 68 + c4] = *(const float4*)&h_act[(node0 + r) * C1 + c4];
    }
    if (tid < NC) { aS[tid] = att_src2[tid]; aD[tid] = att_dst2[tid]; }
    __syncthreads();

    int node_l = tid >> 4, c = tid & 15;
    const float* hr = &hS[node_l * 68];
    float acc = 0.f;
#pragma unroll 8
    for (int k = 0; k < C1; k++) acc += hr[k] * wS[k * NC + c];
    int node = node0 + node_l;
    h2[node * NC + c] = acc;

    float ps = acc * aS[c], pd = acc * aD[c];
    for (int off = 8; off; off >>= 1) { ps += __shfl_xor(ps, off); pd += __shfl_xor(pd, off); }
    if (c == 0) { a_src2[node] = ps; a_dst2[node] = pd; }
}

// ---------------- layer 2 softmax-aggregate + log_softmax ----------------
__global__ __launch_bounds__(256) void k_agg2(
    const float* __restrict__ h2, const float* __restrict__ a_src2,
    const float* __restrict__ a_dst2, const int* __restrict__ rowptr,
    const int* __restrict__ csr_src, const float* __restrict__ b2,
    float* __restrict__ out_lsm) {
    int lane = threadIdx.x & 63;
    int node = blockIdx.x * 4 + (threadIdx.x >> 6);
    int esub = lane >> 4, c = lane & 15;
    int rs = rowptr[node];
    int deg = rowptr[node + 1] - rs;

    float adst = a_dst2[node];
    float e0 = lrelu(a_src2[node] + adst);
    float m = e0;
    for (int base = 0; base < deg; base += 64) {
        int idx = base + lane;
        if (idx < deg) m = fmaxf(m, lrelu(a_src2[csr_src[rs + idx]] + adst));
    }
    for (int off = 32; off; off >>= 1) m = fmaxf(m, __shfl_xor(m, off));

    float w0 = __expf(e0 - m);
    float sacc = (esub == 0) ? w0 : 0.f;
    float acc  = (esub == 0) ? w0 * h2[node * NC + c] : 0.f;

    for (int base = 0; base < deg; base += 64) {
        int idx = base + lane;
        int s_l = 0; float w_l = 0.f;
        if (idx < deg) {                           // lane-parallel weight precompute
            s_l = csr_src[rs + idx];
            w_l = __expf(lrelu(a_src2[s_l] + adst) - m);
        }
        int nrem = min(64, deg - base);
        for (int j2 = 0; j2 < nrem; j2 += 4) {     // 4 edges x 16 cols in flight
            int jj = j2 + esub;
            int sel = (jj < nrem) ? jj : 0;
            int s = __shfl(s_l, sel);
            float wj = __shfl(w_l, sel);
            if (jj >= nrem) wj = 0.f;
            sacc += wj;
            acc += wj * h2[s * NC + c];
        }
    }
    acc  += __shfl_xor(acc, 16);  acc  += __shfl_xor(acc, 32);
    sacc += __shfl_xor(sacc, 16); sacc += __shfl_xor(sacc, 32);

    float logit = acc / sacc + b2[c];
    float mxl = logit;
    for (int off = 8; off; off >>= 1) mxl = fmaxf(mxl, __shfl_xor(mxl, off));
    float ex = __expf(logit - mxl);
    float se = ex;
    for (int off = 8; off; off >>= 1) se += __shfl_xor(se, off);
    float lsm = (logit - mxl) - __logf(se);
    if (esub == 0) out_lsm[node * NC + c] = lsm;
}

extern "C" void kernel_launch(void* const* d_in, const int* in_sizes, int n_in,
                              void* d_out, int out_size, void* d_ws, size_t ws_size,
                              hipStream_t stream) {
    const float* x   = (const float*)d_in[0];
    const int* ei    = (const int*)d_in[1];   // [2,E]: src row then dst row
    const float* W1  = (const float*)d_in[2];
    const float* as1 = (const float*)d_in[3];
    const float* ad1 = (const float*)d_in[4];
    const float* b1  = (const float*)d_in[5];
    const float* W2  = (const float*)d_in[6];
    const float* as2 = (const float*)d_in[7];
    const float* ad2 = (const float*)d_in[8];
    const float* b2  = (const float*)d_in[9];
    float* out = (float*)d_out;               // [N*16 log_softmax][N*64 embeddings]
    float* out_lsm = out;
    float* out_emb = out + (size_t)N_NODES * NC;

    float* ws = (float*)d_ws;
    float* h1     = ws;                              // N*64
    float* a_src1 = h1     + (size_t)N_NODES * C1;   // N*4
    float* a_dst1 = a_src1 + (size_t)N_NODES * 4;    // N*4
    float* h2     = a_dst1 + (size_t)N_NODES * 4;    // N*16
    float* a_src2 = h2     + (size_t)N_NODES * NC;   // N
    float* a_dst2 = a_src2 + (size_t)N_NODES;        // N
    int*   deg    = (int*)(a_dst2 + N_NODES);        // N
    int*   cnt    = deg + N_NODES;                   // N
    int*   rowptr = cnt + N_NODES;                   // N+1
    int*   csr    = rowptr + N_NODES + 1;            // E
    // total ws use: ~36 MB floats + ~7.6 MB ints = ~44 MB

    const int* e_src = ei;
    const int* e_dst = ei + N_EDGES;

    hipMemsetAsync(deg, 0, 2 * (size_t)N_NODES * sizeof(int), stream);  // deg + cnt
    k_hist   <<<N_EDGES / 256, 256, 0, stream>>>(e_dst, deg);
    k_scan   <<<1, 1024, 0, stream>>>(deg, rowptr);
    k_scatter<<<N_EDGES / 256, 256, 0, stream>>>(e_src, e_dst, rowptr, cnt, csr);

    k_gemm1<<<N_NODES / 16, 256, 0, stream>>>(x, W1, as1, ad1, h1, a_src1, a_dst1);
    k_agg1 <<<N_NODES / 4, 256, 0, stream>>>(h1, a_src1, a_dst1, rowptr, csr, b1, out_emb);
    k_gemm2<<<N_NODES / 16, 256, 0, stream>>>(out_emb, W2, as2, ad2, h2, a_src2, a_dst2);
    k_agg2 <<<N_NODES / 4, 256, 0, stream>>>(h2, a_src2, a_dst2, rowptr, csr, b2, out_lsm);
}

// Round 3
// 536.653 us; speedup vs baseline: 1.2935x; 1.2935x over previous
//
#include <hip/hip_runtime.h>
#include <hip/hip_bf16.h>

#define N_NODES 100000
#define N_EDGES 1600000
#define IN_F 128
#define C1 64      // HEADS*HID
#define NC 16      // classes / layer2 width

#define SCAN_TILE 1024
#define SCAN_NB ((N_NODES + SCAN_TILE - 1) / SCAN_TILE)   // 98 blocks

__device__ __forceinline__ float lrelu(float x) { return fmaxf(x, 0.2f * x); }

// ---------------- CSR build ----------------
__global__ void k_hist(const int* __restrict__ dst, int* __restrict__ deg) {
    int e = blockIdx.x * 256 + threadIdx.x;          // grid exactly E/256
    atomicAdd(&deg[dst[e]], 1);
}

// pass 1: per-block sums of deg (1024 elems per 256-thread block)
__global__ __launch_bounds__(256) void k_scan1(const int* __restrict__ deg,
                                               int* __restrict__ partial) {
    __shared__ int wsum[4];
    int tid = threadIdx.x;
    int i0 = blockIdx.x * SCAN_TILE + tid * 4;
    int s = 0;
#pragma unroll
    for (int j = 0; j < 4; j++) { int i = i0 + j; if (i < N_NODES) s += deg[i]; }
    for (int off = 32; off; off >>= 1) s += __shfl_xor(s, off);
    if ((tid & 63) == 0) wsum[tid >> 6] = s;
    __syncthreads();
    if (tid == 0) partial[blockIdx.x] = wsum[0] + wsum[1] + wsum[2] + wsum[3];
}

// pass 2: exclusive scan of the 98 partials (single tiny block)
__global__ void k_scan2(const int* __restrict__ partial, int* __restrict__ pscan,
                        int* __restrict__ rowptr) {
    __shared__ int buf[128];
    int tid = threadIdx.x;
    int v = (tid < SCAN_NB) ? partial[tid] : 0;
    buf[tid] = v;
    __syncthreads();
    for (int d = 1; d < 128; d <<= 1) {
        int t = (tid >= d) ? buf[tid - d] : 0;
        __syncthreads();
        buf[tid] += t;
        __syncthreads();
    }
    if (tid < SCAN_NB) pscan[tid] = buf[tid] - v;    // exclusive
    if (tid == 0) rowptr[N_NODES] = N_EDGES;         // total is static
}

// pass 3: block-local exclusive scan + block offset -> rowptr
__global__ __launch_bounds__(256) void k_scan3(const int* __restrict__ deg,
                                               const int* __restrict__ pscan,
                                               int* __restrict__ rowptr) {
    __shared__ int wsum[4];
    int tid = threadIdx.x, lane = tid & 63, wave = tid >> 6;
    int i0 = blockIdx.x * SCAN_TILE + tid * 4;
    int v0 = 0, v1 = 0, v2 = 0, v3 = 0;
    if (i0 + 0 < N_NODES) v0 = deg[i0 + 0];
    if (i0 + 1 < N_NODES) v1 = deg[i0 + 1];
    if (i0 + 2 < N_NODES) v2 = deg[i0 + 2];
    if (i0 + 3 < N_NODES) v3 = deg[i0 + 3];
    int s0 = v0, s1 = s0 + v1, s2 = s1 + v2, s3 = s2 + v3;   // thread-local inclusive
    int t = s3;                                              // wave inclusive scan
    for (int off = 1; off < 64; off <<= 1) {
        int u = __shfl_up(t, off);
        if (lane >= off) t += u;
    }
    if (lane == 63) wsum[wave] = t;
    __syncthreads();
    int woff = 0;
    for (int w = 0; w < wave; w++) woff += wsum[w];
    int base = pscan[blockIdx.x] + woff + (t - s3);          // exclusive prefix
    if (i0 + 0 < N_NODES) rowptr[i0 + 0] = base;
    if (i0 + 1 < N_NODES) rowptr[i0 + 1] = base + s0;
    if (i0 + 2 < N_NODES) rowptr[i0 + 2] = base + s1;
    if (i0 + 3 < N_NODES) rowptr[i0 + 3] = base + s2;
}

__global__ void k_scatter(const int* __restrict__ src, const int* __restrict__ dst,
                          const int* __restrict__ rowptr, int* __restrict__ cnt,
                          int* __restrict__ csr_src) {
    int e = blockIdx.x * 256 + threadIdx.x;
    int d = dst[e];
    int k = atomicAdd(&cnt[d], 1);
    csr_src[rowptr[d] + k] = src[e];
}

// ---------------- layer 1 GEMM + attention dots ----------------
// 16 nodes per 256-thread block; thread t: node_l = t>>4, cols (t&15)*4 .. +3
__global__ __launch_bounds__(256) void k_gemm1(
    const float* __restrict__ x, const float* __restrict__ W1,
    const float* __restrict__ att_src1, const float* __restrict__ att_dst1,
    float* __restrict__ h1, float* __restrict__ a_src1, float* __restrict__ a_dst1) {
    __shared__ __align__(16) float wS[IN_F * C1];   // 32 KB, [k][col]
    __shared__ __align__(16) float xS[16 * 132];    // stride 132: aligned + conflict-free
    __shared__ float aSs[C1], aSd[C1];
    int tid = threadIdx.x;
    int node0 = blockIdx.x * 16;
    for (int i = tid; i < (IN_F * C1) / 4; i += 256)
        *(float4*)&wS[i * 4] = *(const float4*)&W1[i * 4];
    for (int i = tid; i < (16 * IN_F) / 4; i += 256) {
        int r = i >> 5, c4 = (i & 31) << 2;          // 32 float4 per 128-wide row
        *(float4*)&xS[r * 132 + c4] = *(const float4*)&x[(node0 + r) * IN_F + c4];
    }
    if (tid < C1) { aSs[tid] = att_src1[tid]; aSd[tid] = att_dst1[tid]; }
    __syncthreads();

    int node_l = tid >> 4;
    int cq = (tid & 15) << 2;
    const float* xrow = &xS[node_l * 132];
    float4 acc = {0.f, 0.f, 0.f, 0.f};
#pragma unroll 4
    for (int k = 0; k < IN_F; k++) {
        float xv = xrow[k];
        float4 wv = *(const float4*)&wS[k * C1 + cq];
        acc.x += xv * wv.x; acc.y += xv * wv.y; acc.z += xv * wv.z; acc.w += xv * wv.w;
    }
    int node = node0 + node_l;
    *(float4*)&h1[node * C1 + cq] = acc;

    float ps = acc.x * aSs[cq] + acc.y * aSs[cq + 1] + acc.z * aSs[cq + 2] + acc.w * aSs[cq + 3];
    float pd = acc.x * aSd[cq] + acc.y * aSd[cq + 1] + acc.z * aSd[cq + 2] + acc.w * aSd[cq + 3];
    ps += __shfl_xor(ps, 1); ps += __shfl_xor(ps, 2);
    pd += __shfl_xor(pd, 1); pd += __shfl_xor(pd, 2);
    if ((tid & 3) == 0) {
        int h = (tid & 15) >> 2;
        a_src1[node * 4 + h] = ps;
        a_dst1[node * 4 + h] = pd;
    }
}

// ---------------- layer 1 segment-softmax + aggregate (one wave per node) ----
__global__ __launch_bounds__(256) void k_agg1(
    const float* __restrict__ h1, const float* __restrict__ a_src1,
    const float* __restrict__ a_dst1, const int* __restrict__ rowptr,
    const int* __restrict__ csr_src, const float* __restrict__ b1,
    float* __restrict__ out_emb) {
    int lane = threadIdx.x & 63;
    int node = blockIdx.x * 4 + (threadIdx.x >> 6);
    int col = lane, h = lane >> 4;
    int rs = rowptr[node];
    int deg = rowptr[node + 1] - rs;

    float4 ad4 = *(const float4*)&a_dst1[node * 4];
    float4 as4 = *(const float4*)&a_src1[node * 4];
    float e0x = lrelu(as4.x + ad4.x), e0y = lrelu(as4.y + ad4.y);
    float e0z = lrelu(as4.z + ad4.z), e0w = lrelu(as4.w + ad4.w);
    float mx = e0x, my = e0y, mz = e0z, mw = e0w;   // self-loop seeds the max

    for (int base = 0; base < deg; base += 64) {    // pass 1: lane-parallel max
        int idx = base + lane;
        if (idx < deg) {
            int s = csr_src[rs + idx];
            float4 as = *(const float4*)&a_src1[s * 4];
            mx = fmaxf(mx, lrelu(as.x + ad4.x));
            my = fmaxf(my, lrelu(as.y + ad4.y));
            mz = fmaxf(mz, lrelu(as.z + ad4.z));
            mw = fmaxf(mw, lrelu(as.w + ad4.w));
        }
    }
    for (int off = 32; off; off >>= 1) {
        mx = fmaxf(mx, __shfl_xor(mx, off));
        my = fmaxf(my, __shfl_xor(my, off));
        mz = fmaxf(mz, __shfl_xor(mz, off));
        mw = fmaxf(mw, __shfl_xor(mw, off));
    }
    float m_h  = (h == 0) ? mx : (h == 1) ? my : (h == 2) ? mz : mw;
    float e0_h = (h == 0) ? e0x : (h == 1) ? e0y : (h == 2) ? e0z : e0w;

    float w0 = __expf(e0_h - m_h);                  // self-loop contribution
    float sacc = w0;
    float acc  = w0 * h1[node * C1 + col];

    for (int base = 0; base < deg; base += 64) {    // pass 2: lane-per-column gather
        int idx = base + lane;
        int s_l = 0;
        float4 w4 = {0.f, 0.f, 0.f, 0.f};
        if (idx < deg) {                            // lane-parallel weight precompute
            s_l = csr_src[rs + idx];
            float4 as = *(const float4*)&a_src1[s_l * 4];
            w4.x = __expf(lrelu(as.x + ad4.x) - mx);
            w4.y = __expf(lrelu(as.y + ad4.y) - my);
            w4.z = __expf(lrelu(as.z + ad4.z) - mz);
            w4.w = __expf(lrelu(as.w + ad4.w) - mw);
        }
        int nrem = min(64, deg - base);
        for (int j = 0; j < nrem; j++) {
            int s = __shfl(s_l, j);
            float wx = __shfl(w4.x, j), wy = __shfl(w4.y, j);
            float wz = __shfl(w4.z, j), ww = __shfl(w4.w, j);
            float wj = (h == 0) ? wx : (h == 1) ? wy : (h == 2) ? wz : ww;
            sacc += wj;
            acc += wj * h1[s * C1 + col];
        }
    }
    float o = acc / sacc + b1[col];
    o = (o > 0.f) ? o : expm1f(o);                  // ELU
    out_emb[node * C1 + col] = o;                   // fp32 embeddings == h_act
}

// ---------------- layer 2 GEMM + attention dots ----------------
__global__ __launch_bounds__(256) void k_gemm2(
    const float* __restrict__ h_act, const float* __restrict__ W2,
    const float* __restrict__ att_src2, const float* __restrict__ att_dst2,
    float* __restrict__ h2, float* __restrict__ a_src2, float* __restrict__ a_dst2) {
    __shared__ float wS[C1 * NC];                 // 4 KB [k][c]
    __shared__ __align__(16) float hS[16 * 68];   // stride 68: aligned + conflict-free
    __shared__ float aS[NC], aD[NC];
    int tid = threadIdx.x;
    int node0 = blockIdx.x * 16;
    if (tid < (C1 * NC) / 4)
        *(float4*)&wS[tid * 4] = *(const float4*)&W2[tid * 4];
    {   // 16 rows x 64 cols of h_act, 256 float4s
        int r = tid >> 4, c4 = (tid & 15) << 2;
        *(float4*)&hS[r * 68 + c4] = *(const float4*)&h_act[(node0 + r) * C1 + c4];
    }
    if (tid < NC) { aS[tid] = att_src2[tid]; aD[tid] = att_dst2[tid]; }
    __syncthreads();

    int node_l = tid >> 4, c = tid & 15;
    const float* hr = &hS[node_l * 68];
    float acc = 0.f;
#pragma unroll 8
    for (int k = 0; k < C1; k++) acc += hr[k] * wS[k * NC + c];
    int node = node0 + node_l;
    h2[node * NC + c] = acc;

    float ps = acc * aS[c], pd = acc * aD[c];
    for (int off = 8; off; off >>= 1) { ps += __shfl_xor(ps, off); pd += __shfl_xor(pd, off); }
    if (c == 0) { a_src2[node] = ps; a_dst2[node] = pd; }
}

// ---------------- layer 2 softmax-aggregate + log_softmax ----------------
__global__ __launch_bounds__(256) void k_agg2(
    const float* __restrict__ h2, const float* __restrict__ a_src2,
    const float* __restrict__ a_dst2, const int* __restrict__ rowptr,
    const int* __restrict__ csr_src, const float* __restrict__ b2,
    float* __restrict__ out_lsm) {
    int lane = threadIdx.x & 63;
    int node = blockIdx.x * 4 + (threadIdx.x >> 6);
    int esub = lane >> 4, c = lane & 15;
    int rs = rowptr[node];
    int deg = rowptr[node + 1] - rs;

    float adst = a_dst2[node];
    float e0 = lrelu(a_src2[node] + adst);
    float m = e0;
    for (int base = 0; base < deg; base += 64) {
        int idx = base + lane;
        if (idx < deg) m = fmaxf(m, lrelu(a_src2[csr_src[rs + idx]] + adst));
    }
    for (int off = 32; off; off >>= 1) m = fmaxf(m, __shfl_xor(m, off));

    float w0 = __expf(e0 - m);
    float sacc = (esub == 0) ? w0 : 0.f;
    float acc  = (esub == 0) ? w0 * h2[node * NC + c] : 0.f;

    for (int base = 0; base < deg; base += 64) {
        int idx = base + lane;
        int s_l = 0; float w_l = 0.f;
        if (idx < deg) {                           // lane-parallel weight precompute
            s_l = csr_src[rs + idx];
            w_l = __expf(lrelu(a_src2[s_l] + adst) - m);
        }
        int nrem = min(64, deg - base);
        for (int j2 = 0; j2 < nrem; j2 += 4) {     // 4 edges x 16 cols in flight
            int jj = j2 + esub;
            int sel = (jj < nrem) ? jj : 0;
            int s = __shfl(s_l, sel);
            float wj = __shfl(w_l, sel);
            if (jj >= nrem) wj = 0.f;
            sacc += wj;
            acc += wj * h2[s * NC + c];
        }
    }
    acc  += __shfl_xor(acc, 16);  acc  += __shfl_xor(acc, 32);
    sacc += __shfl_xor(sacc, 16); sacc += __shfl_xor(sacc, 32);

    float logit = acc / sacc + b2[c];
    float mxl = logit;
    for (int off = 8; off; off >>= 1) mxl = fmaxf(mxl, __shfl_xor(mxl, off));
    float ex = __expf(logit - mxl);
    float se = ex;
    for (int off = 8; off; off >>= 1) se += __shfl_xor(se, off);
    float lsm = (logit - mxl) - __logf(se);
    if (esub == 0) out_lsm[node * NC + c] = lsm;
}

extern "C" void kernel_launch(void* const* d_in, const int* in_sizes, int n_in,
                              void* d_out, int out_size, void* d_ws, size_t ws_size,
                              hipStream_t stream) {
    const float* x   = (const float*)d_in[0];
    const int* ei    = (const int*)d_in[1];   // [2,E]: src row then dst row
    const float* W1  = (const float*)d_in[2];
    const float* as1 = (const float*)d_in[3];
    const float* ad1 = (const float*)d_in[4];
    const float* b1  = (const float*)d_in[5];
    const float* W2  = (const float*)d_in[6];
    const float* as2 = (const float*)d_in[7];
    const float* ad2 = (const float*)d_in[8];
    const float* b2  = (const float*)d_in[9];
    float* out = (float*)d_out;               // [N*16 log_softmax][N*64 embeddings]
    float* out_lsm = out;
    float* out_emb = out + (size_t)N_NODES * NC;

    float* ws = (float*)d_ws;
    float* h1     = ws;                              // N*64
    float* a_src1 = h1     + (size_t)N_NODES * C1;   // N*4
    float* a_dst1 = a_src1 + (size_t)N_NODES * 4;    // N*4
    float* h2     = a_dst1 + (size_t)N_NODES * 4;    // N*16
    float* a_src2 = h2     + (size_t)N_NODES * NC;   // N
    float* a_dst2 = a_src2 + (size_t)N_NODES;        // N
    int*   deg    = (int*)(a_dst2 + N_NODES);        // N
    int*   cnt    = deg + N_NODES;                   // N
    int*   rowptr = cnt + N_NODES;                   // N+1
    int*   csr    = rowptr + N_NODES + 1;            // E
    int*   partial= csr + N_EDGES;                   // SCAN_NB
    int*   pscan  = partial + SCAN_NB;               // SCAN_NB
    // total ws use: ~36 MB floats + ~7.6 MB ints

    const int* e_src = ei;
    const int* e_dst = ei + N_EDGES;

    hipMemsetAsync(deg, 0, 2 * (size_t)N_NODES * sizeof(int), stream);  // deg + cnt
    k_hist   <<<N_EDGES / 256, 256, 0, stream>>>(e_dst, deg);
    k_scan1  <<<SCAN_NB, 256, 0, stream>>>(deg, partial);
    k_scan2  <<<1, 128, 0, stream>>>(partial, pscan, rowptr);
    k_scan3  <<<SCAN_NB, 256, 0, stream>>>(deg, pscan, rowptr);
    k_scatter<<<N_EDGES / 256, 256, 0, stream>>>(e_src, e_dst, rowptr, cnt, csr);

    k_gemm1<<<N_NODES / 16, 256, 0, stream>>>(x, W1, as1, ad1, h1, a_src1, a_dst1);
    k_agg1 <<<N_NODES / 4, 256, 0, stream>>>(h1, a_src1, a_dst1, rowptr, csr, b1, out_emb);
    k_gemm2<<<N_NODES / 16, 256, 0, stream>>>(out_emb, W2, as2, ad2, h2, a_src2, a_dst2);
    k_agg2 <<<N_NODES / 4, 256, 0, stream>>>(h2, a_src2, a_dst2, rowptr, csr, b2, out_lsm);
}

// Round 4
// 504.399 us; speedup vs baseline: 1.3762x; 1.0639x over previous
//
#include <hip/hip_runtime.h>
#include <hip/hip_bf16.h>

#define N_NODES 100000
#define N_EDGES 1600000
#define IN_F 128
#define C1 64      // HEADS*HID
#define NC 16      // classes / layer2 width

#define SCAN_TILE 1024
#define SCAN_NB ((N_NODES + SCAN_TILE - 1) / SCAN_TILE)   // 98 blocks

__device__ __forceinline__ float lrelu(float x) { return fmaxf(x, 0.2f * x); }
__device__ __forceinline__ float selh(float4 v, int h) {
    return (h == 0) ? v.x : (h == 1) ? v.y : (h == 2) ? v.z : v.w;
}

// ---------------- CSR build ----------------
__global__ void k_hist(const int* __restrict__ dst, int* __restrict__ deg) {
    int e = blockIdx.x * 256 + threadIdx.x;          // grid exactly E/256
    atomicAdd(&deg[dst[e]], 1);
}

// pass 1: per-block sums of deg (1024 elems per 256-thread block)
__global__ __launch_bounds__(256) void k_scan1(const int* __restrict__ deg,
                                               int* __restrict__ partial) {
    __shared__ int wsum[4];
    int tid = threadIdx.x;
    int i0 = blockIdx.x * SCAN_TILE + tid * 4;
    int s = 0;
#pragma unroll
    for (int j = 0; j < 4; j++) { int i = i0 + j; if (i < N_NODES) s += deg[i]; }
    for (int off = 32; off; off >>= 1) s += __shfl_xor(s, off);
    if ((tid & 63) == 0) wsum[tid >> 6] = s;
    __syncthreads();
    if (tid == 0) partial[blockIdx.x] = wsum[0] + wsum[1] + wsum[2] + wsum[3];
}

// pass 2: exclusive scan of the 98 partials (single tiny block)
__global__ void k_scan2(const int* __restrict__ partial, int* __restrict__ pscan,
                        int* __restrict__ rowptr) {
    __shared__ int buf[128];
    int tid = threadIdx.x;
    int v = (tid < SCAN_NB) ? partial[tid] : 0;
    buf[tid] = v;
    __syncthreads();
    for (int d = 1; d < 128; d <<= 1) {
        int t = (tid >= d) ? buf[tid - d] : 0;
        __syncthreads();
        buf[tid] += t;
        __syncthreads();
    }
    if (tid < SCAN_NB) pscan[tid] = buf[tid] - v;    // exclusive
    if (tid == 0) rowptr[N_NODES] = N_EDGES;         // total is static
}

// pass 3: block-local exclusive scan + block offset -> rowptr
__global__ __launch_bounds__(256) void k_scan3(const int* __restrict__ deg,
                                               const int* __restrict__ pscan,
                                               int* __restrict__ rowptr) {
    __shared__ int wsum[4];
    int tid = threadIdx.x, lane = tid & 63, wave = tid >> 6;
    int i0 = blockIdx.x * SCAN_TILE + tid * 4;
    int v0 = 0, v1 = 0, v2 = 0, v3 = 0;
    if (i0 + 0 < N_NODES) v0 = deg[i0 + 0];
    if (i0 + 1 < N_NODES) v1 = deg[i0 + 1];
    if (i0 + 2 < N_NODES) v2 = deg[i0 + 2];
    if (i0 + 3 < N_NODES) v3 = deg[i0 + 3];
    int s0 = v0, s1 = s0 + v1, s2 = s1 + v2, s3 = s2 + v3;   // thread-local inclusive
    int t = s3;                                              // wave inclusive scan
    for (int off = 1; off < 64; off <<= 1) {
        int u = __shfl_up(t, off);
        if (lane >= off) t += u;
    }
    if (lane == 63) wsum[wave] = t;
    __syncthreads();
    int woff = 0;
    for (int w = 0; w < wave; w++) woff += wsum[w];
    int base = pscan[blockIdx.x] + woff + (t - s3);          // exclusive prefix
    if (i0 + 0 < N_NODES) rowptr[i0 + 0] = base;
    if (i0 + 1 < N_NODES) rowptr[i0 + 1] = base + s0;
    if (i0 + 2 < N_NODES) rowptr[i0 + 2] = base + s1;
    if (i0 + 3 < N_NODES) rowptr[i0 + 3] = base + s2;
}

__global__ void k_scatter(const int* __restrict__ src, const int* __restrict__ dst,
                          const int* __restrict__ rowptr, int* __restrict__ cnt,
                          int* __restrict__ csr_src) {
    int e = blockIdx.x * 256 + threadIdx.x;
    int d = dst[e];
    int k = atomicAdd(&cnt[d], 1);
    csr_src[rowptr[d] + k] = src[e];
}

// ---------------- layer 1 GEMM + attention dots ----------------
// 16 nodes per 256-thread block; thread t: node_l = t>>4, cols (t&15)*4 .. +3
__global__ __launch_bounds__(256) void k_gemm1(
    const float* __restrict__ x, const float* __restrict__ W1,
    const float* __restrict__ att_src1, const float* __restrict__ att_dst1,
    float* __restrict__ h1, float* __restrict__ a_src1, float* __restrict__ a_dst1) {
    __shared__ __align__(16) float wS[IN_F * C1];   // 32 KB, [k][col]
    __shared__ __align__(16) float xS[16 * 132];    // stride 132: aligned + conflict-free
    __shared__ float aSs[C1], aSd[C1];
    int tid = threadIdx.x;
    int node0 = blockIdx.x * 16;
    for (int i = tid; i < (IN_F * C1) / 4; i += 256)
        *(float4*)&wS[i * 4] = *(const float4*)&W1[i * 4];
    for (int i = tid; i < (16 * IN_F) / 4; i += 256) {
        int r = i >> 5, c4 = (i & 31) << 2;          // 32 float4 per 128-wide row
        *(float4*)&xS[r * 132 + c4] = *(const float4*)&x[(node0 + r) * IN_F + c4];
    }
    if (tid < C1) { aSs[tid] = att_src1[tid]; aSd[tid] = att_dst1[tid]; }
    __syncthreads();

    int node_l = tid >> 4;
    int cq = (tid & 15) << 2;
    const float* xrow = &xS[node_l * 132];
    float4 acc = {0.f, 0.f, 0.f, 0.f};
#pragma unroll 4
    for (int k = 0; k < IN_F; k++) {
        float xv = xrow[k];
        float4 wv = *(const float4*)&wS[k * C1 + cq];
        acc.x += xv * wv.x; acc.y += xv * wv.y; acc.z += xv * wv.z; acc.w += xv * wv.w;
    }
    int node = node0 + node_l;
    *(float4*)&h1[node * C1 + cq] = acc;

    float ps = acc.x * aSs[cq] + acc.y * aSs[cq + 1] + acc.z * aSs[cq + 2] + acc.w * aSs[cq + 3];
    float pd = acc.x * aSd[cq] + acc.y * aSd[cq + 1] + acc.z * aSd[cq + 2] + acc.w * aSd[cq + 3];
    ps += __shfl_xor(ps, 1); ps += __shfl_xor(ps, 2);
    pd += __shfl_xor(pd, 1); pd += __shfl_xor(pd, 2);
    if ((tid & 3) == 0) {
        int h = (tid & 15) >> 2;
        a_src1[node * 4 + h] = ps;
        a_dst1[node * 4 + h] = pd;
    }
}

// ---------------- layer 1 segment-softmax + aggregate (one wave per node) ----
// LDS-staged (src, weight) pairs; serial loop = 1 ds_read_b64 + 1 global row + 1 FMA
__global__ __launch_bounds__(256) void k_agg1(
    const float* __restrict__ h1, const float* __restrict__ a_src1,
    const float* __restrict__ a_dst1, const int* __restrict__ rowptr,
    const int* __restrict__ csr_src, const float* __restrict__ b1,
    float* __restrict__ out_emb) {
    __shared__ int2 swS[4][4][65];   // [wave][head][edge] = (src, w_h); 65: head arrays on distinct bank pairs
    int tid = threadIdx.x;
    int lane = tid & 63, wave = tid >> 6;
    int node = blockIdx.x * 4 + wave;
    int col = lane, h = lane >> 4;
    int rs = rowptr[node];
    int deg = rowptr[node + 1] - rs;

    float4 ad4 = *(const float4*)&a_dst1[node * 4];
    float4 as4 = *(const float4*)&a_src1[node * 4];
    float4 e04 = {lrelu(as4.x + ad4.x), lrelu(as4.y + ad4.y),
                  lrelu(as4.z + ad4.z), lrelu(as4.w + ad4.w)};
    float mx = e04.x, my = e04.y, mz = e04.z, mw = e04.w;   // self-loop seeds the max

    for (int base = 0; base < deg; base += 64) {    // pass 1: lane-parallel max
        int idx = base + lane;
        if (idx < deg) {
            int s = csr_src[rs + idx];
            float4 as = *(const float4*)&a_src1[s * 4];
            mx = fmaxf(mx, lrelu(as.x + ad4.x));
            my = fmaxf(my, lrelu(as.y + ad4.y));
            mz = fmaxf(mz, lrelu(as.z + ad4.z));
            mw = fmaxf(mw, lrelu(as.w + ad4.w));
        }
    }
    for (int off = 32; off; off >>= 1) {
        mx = fmaxf(mx, __shfl_xor(mx, off));
        my = fmaxf(my, __shfl_xor(my, off));
        mz = fmaxf(mz, __shfl_xor(mz, off));
        mw = fmaxf(mw, __shfl_xor(mw, off));
    }
    float m_h  = (h == 0) ? mx : (h == 1) ? my : (h == 2) ? mz : mw;
    float e0_h = selh(e04, h);

    float w0 = __expf(e0_h - m_h);                  // self-loop contribution
    float acc = w0 * h1[node * C1 + col];
    float4 sac4 = {0.f, 0.f, 0.f, 0.f};            // lane-parallel denominator

    for (int base = 0; base < deg; base += 64) {
        int idx = base + lane;
        int s_l = 0;
        float4 w4 = {0.f, 0.f, 0.f, 0.f};
        if (idx < deg) {                            // lane-parallel weight compute
            s_l = csr_src[rs + idx];
            float4 as = *(const float4*)&a_src1[s_l * 4];
            w4.x = __expf(lrelu(as.x + ad4.x) - mx);
            w4.y = __expf(lrelu(as.y + ad4.y) - my);
            w4.z = __expf(lrelu(as.z + ad4.z) - mz);
            w4.w = __expf(lrelu(as.w + ad4.w) - mw);
        }
        sac4.x += w4.x; sac4.y += w4.y; sac4.z += w4.z; sac4.w += w4.w;
        swS[wave][0][lane] = make_int2(s_l, __float_as_int(w4.x));
        swS[wave][1][lane] = make_int2(s_l, __float_as_int(w4.y));
        swS[wave][2][lane] = make_int2(s_l, __float_as_int(w4.z));
        swS[wave][3][lane] = make_int2(s_l, __float_as_int(w4.w));
        int nrem = min(64, deg - base);
        for (int j = 0; j < nrem; j++) {            // serial: broadcast ds_read_b64
            int2 p = swS[wave][h][j];
            acc = fmaf(__int_as_float(p.y), h1[p.x * C1 + col], acc);
        }
    }
    for (int off = 32; off; off >>= 1) {            // reduce denominator (once)
        sac4.x += __shfl_xor(sac4.x, off);
        sac4.y += __shfl_xor(sac4.y, off);
        sac4.z += __shfl_xor(sac4.z, off);
        sac4.w += __shfl_xor(sac4.w, off);
    }
    float sacc = selh(sac4, h) + w0;

    float o = acc / sacc + b1[col];
    o = (o > 0.f) ? o : expm1f(o);                  // ELU
    out_emb[node * C1 + col] = o;                   // fp32 embeddings == h_act
}

// ---------------- layer 2 GEMM + attention dots ----------------
__global__ __launch_bounds__(256) void k_gemm2(
    const float* __restrict__ h_act, const float* __restrict__ W2,
    const float* __restrict__ att_src2, const float* __restrict__ att_dst2,
    float* __restrict__ h2, float* __restrict__ a_src2, float* __restrict__ a_dst2) {
    __shared__ float wS[C1 * NC];                 // 4 KB [k][c]
    __shared__ __align__(16) float hS[16 * 68];   // stride 68: aligned + conflict-free
    __shared__ float aS[NC], aD[NC];
    int tid = threadIdx.x;
    int node0 = blockIdx.x * 16;
    if (tid < (C1 * NC) / 4)
        *(float4*)&wS[tid * 4] = *(const float4*)&W2[tid * 4];
    {   // 16 rows x 64 cols of h_act, 256 float4s
        int r = tid >> 4, c4 = (tid & 15) << 2;
        *(float4*)&hS[r * 68 + c4] = *(const float4*)&h_act[(node0 + r) * C1 + c4];
    }
    if (tid < NC) { aS[tid] = att_src2[tid]; aD[tid] = att_dst2[tid]; }
    __syncthreads();

    int node_l = tid >> 4, c = tid & 15;
    const float* hr = &hS[node_l * 68];
    float acc = 0.f;
#pragma unroll 8
    for (int k = 0; k < C1; k++) acc += hr[k] * wS[k * NC + c];
    int node = node0 + node_l;
    h2[node * NC + c] = acc;

    float ps = acc * aS[c], pd = acc * aD[c];
    for (int off = 8; off; off >>= 1) { ps += __shfl_xor(ps, off); pd += __shfl_xor(pd, off); }
    if (c == 0) { a_src2[node] = ps; a_dst2[node] = pd; }
}

// ---------------- layer 2 softmax-aggregate + log_softmax ----------------
__global__ __launch_bounds__(256) void k_agg2(
    const float* __restrict__ h2, const float* __restrict__ a_src2,
    const float* __restrict__ a_dst2, const int* __restrict__ rowptr,
    const int* __restrict__ csr_src, const float* __restrict__ b2,
    float* __restrict__ out_lsm) {
    __shared__ int2 swS[4][64];                     // [wave][edge] = (src, w)
    int tid = threadIdx.x;
    int lane = tid & 63, wave = tid >> 6;
    int node = blockIdx.x * 4 + wave;
    int esub = lane >> 4, c = lane & 15;
    int rs = rowptr[node];
    int deg = rowptr[node + 1] - rs;

    float adst = a_dst2[node];
    float e0 = lrelu(a_src2[node] + adst);
    float m = e0;
    for (int base = 0; base < deg; base += 64) {
        int idx = base + lane;
        if (idx < deg) m = fmaxf(m, lrelu(a_src2[csr_src[rs + idx]] + adst));
    }
    for (int off = 32; off; off >>= 1) m = fmaxf(m, __shfl_xor(m, off));

    float w0 = __expf(e0 - m);
    float sacc_l = 0.f;                             // lane-parallel denominator
    float acc = (esub == 0) ? w0 * h2[node * NC + c] : 0.f;

    for (int base = 0; base < deg; base += 64) {
        int idx = base + lane;
        int s_l = 0; float w_l = 0.f;
        if (idx < deg) {                            // lane-parallel weight compute
            s_l = csr_src[rs + idx];
            w_l = __expf(lrelu(a_src2[s_l] + adst) - m);
        }
        sacc_l += w_l;
        swS[wave][lane] = make_int2(s_l, __float_as_int(w_l));
        int nrem = min(64, deg - base);
        for (int j2 = 0; j2 < nrem; j2 += 4) {      // 4 edges x 16 cols in flight
            int2 p = swS[wave][j2 + esub];          // slots >= nrem carry w=0
            acc = fmaf(__int_as_float(p.y), h2[p.x * NC + c], acc);
        }
    }
    acc += __shfl_xor(acc, 16); acc += __shfl_xor(acc, 32);
    for (int off = 32; off; off >>= 1) sacc_l += __shfl_xor(sacc_l, off);
    float sacc = sacc_l + w0;

    float logit = acc / sacc + b2[c];
    float mxl = logit;
    for (int off = 8; off; off >>= 1) mxl = fmaxf(mxl, __shfl_xor(mxl, off));
    float ex = __expf(logit - mxl);
    float se = ex;
    for (int off = 8; off; off >>= 1) se += __shfl_xor(se, off);
    float lsm = (logit - mxl) - __logf(se);
    if (esub == 0) out_lsm[node * NC + c] = lsm;
}

extern "C" void kernel_launch(void* const* d_in, const int* in_sizes, int n_in,
                              void* d_out, int out_size, void* d_ws, size_t ws_size,
                              hipStream_t stream) {
    const float* x   = (const float*)d_in[0];
    const int* ei    = (const int*)d_in[1];   // [2,E]: src row then dst row
    const float* W1  = (const float*)d_in[2];
    const float* as1 = (const float*)d_in[3];
    const float* ad1 = (const float*)d_in[4];
    const float* b1  = (const float*)d_in[5];
    const float* W2  = (const float*)d_in[6];
    const float* as2 = (const float*)d_in[7];
    const float* ad2 = (const float*)d_in[8];
    const float* b2  = (const float*)d_in[9];
    float* out = (float*)d_out;               // [N*16 log_softmax][N*64 embeddings]
    float* out_lsm = out;
    float* out_emb = out + (size_t)N_NODES * NC;

    float* ws = (float*)d_ws;
    float* h1     = ws;                              // N*64
    float* a_src1 = h1     + (size_t)N_NODES * C1;   // N*4
    float* a_dst1 = a_src1 + (size_t)N_NODES * 4;    // N*4
    float* h2     = a_dst1 + (size_t)N_NODES * 4;    // N*16
    float* a_src2 = h2     + (size_t)N_NODES * NC;   // N
    float* a_dst2 = a_src2 + (size_t)N_NODES;        // N
    int*   deg    = (int*)(a_dst2 + N_NODES);        // N
    int*   cnt    = deg + N_NODES;                   // N
    int*   rowptr = cnt + N_NODES;                   // N+1
    int*   csr    = rowptr + N_NODES + 1;            // E
    int*   partial= csr + N_EDGES;                   // SCAN_NB
    int*   pscan  = partial + SCAN_NB;               // SCAN_NB

    const int* e_src = ei;
    const int* e_dst = ei + N_EDGES;

    hipMemsetAsync(deg, 0, 2 * (size_t)N_NODES * sizeof(int), stream);  // deg + cnt
    k_hist   <<<N_EDGES / 256, 256, 0, stream>>>(e_dst, deg);
    k_scan1  <<<SCAN_NB, 256, 0, stream>>>(deg, partial);
    k_scan2  <<<1, 128, 0, stream>>>(partial, pscan, rowptr);
    k_scan3  <<<SCAN_NB, 256, 0, stream>>>(deg, pscan, rowptr);
    k_scatter<<<N_EDGES / 256, 256, 0, stream>>>(e_src, e_dst, rowptr, cnt, csr);

    k_gemm1<<<N_NODES / 16, 256, 0, stream>>>(x, W1, as1, ad1, h1, a_src1, a_dst1);
    k_agg1 <<<N_NODES / 4, 256, 0, stream>>>(h1, a_src1, a_dst1, rowptr, csr, b1, out_emb);
    k_gemm2<<<N_NODES / 16, 256, 0, stream>>>(out_emb, W2, as2, ad2, h2, a_src2, a_dst2);
    k_agg2 <<<N_NODES / 4, 256, 0, stream>>>(h2, a_src2, a_dst2, rowptr, csr, b2, out_lsm);
}

// Round 5
// 449.851 us; speedup vs baseline: 1.5430x; 1.1213x over previous
//
#include <hip/hip_runtime.h>
#include <hip/hip_bf16.h>

#define N_NODES 100000
#define N_EDGES 1600000
#define IN_F 128
#define C1 64      // HEADS*HID
#define NC 16      // classes / layer2 width

#define SCAN_TILE 1024
#define SCAN_NB ((N_NODES + SCAN_TILE - 1) / SCAN_TILE)   // 98 blocks
#define GEMM1_NB (N_NODES / 16)                           // 6250
#define SCAT_NB ((N_EDGES + 1023) / 1024)                 // 1563 (4 edges/thread)

__device__ __forceinline__ float lrelu(float x) { return fmaxf(x, 0.2f * x); }
__device__ __forceinline__ float selh(float4 v, int h) {
    return (h == 0) ? v.x : (h == 1) ? v.y : (h == 2) ? v.z : v.w;
}

// ---------------- CSR build ----------------
__global__ void k_hist(const int* __restrict__ dst, int* __restrict__ deg) {
    int e = blockIdx.x * 256 + threadIdx.x;          // grid exactly E/256
    atomicAdd(&deg[dst[e]], 1);
}

// pass 1: per-block sums of deg (1024 elems per 256-thread block)
__global__ __launch_bounds__(256) void k_scan1(const int* __restrict__ deg,
                                               int* __restrict__ partial) {
    __shared__ int wsum[4];
    int tid = threadIdx.x;
    int i0 = blockIdx.x * SCAN_TILE + tid * 4;
    int s = 0;
#pragma unroll
    for (int j = 0; j < 4; j++) { int i = i0 + j; if (i < N_NODES) s += deg[i]; }
    for (int off = 32; off; off >>= 1) s += __shfl_xor(s, off);
    if ((tid & 63) == 0) wsum[tid >> 6] = s;
    __syncthreads();
    if (tid == 0) partial[blockIdx.x] = wsum[0] + wsum[1] + wsum[2] + wsum[3];
}

// pass 2: exclusive scan of the 98 partials (single tiny block)
__global__ void k_scan2(const int* __restrict__ partial, int* __restrict__ pscan,
                        int* __restrict__ rowptr) {
    __shared__ int buf[128];
    int tid = threadIdx.x;
    int v = (tid < SCAN_NB) ? partial[tid] : 0;
    buf[tid] = v;
    __syncthreads();
    for (int d = 1; d < 128; d <<= 1) {
        int t = (tid >= d) ? buf[tid - d] : 0;
        __syncthreads();
        buf[tid] += t;
        __syncthreads();
    }
    if (tid < SCAN_NB) pscan[tid] = buf[tid] - v;    // exclusive
    if (tid == 0) rowptr[N_NODES] = N_EDGES;         // total is static
}

// pass 3: block-local exclusive scan + block offset -> rowptr
__global__ __launch_bounds__(256) void k_scan3(const int* __restrict__ deg,
                                               const int* __restrict__ pscan,
                                               int* __restrict__ rowptr) {
    __shared__ int wsum[4];
    int tid = threadIdx.x, lane = tid & 63, wave = tid >> 6;
    int i0 = blockIdx.x * SCAN_TILE + tid * 4;
    int v0 = 0, v1 = 0, v2 = 0, v3 = 0;
    if (i0 + 0 < N_NODES) v0 = deg[i0 + 0];
    if (i0 + 1 < N_NODES) v1 = deg[i0 + 1];
    if (i0 + 2 < N_NODES) v2 = deg[i0 + 2];
    if (i0 + 3 < N_NODES) v3 = deg[i0 + 3];
    int s0 = v0, s1 = s0 + v1, s2 = s1 + v2, s3 = s2 + v3;   // thread-local inclusive
    int t = s3;                                              // wave inclusive scan
    for (int off = 1; off < 64; off <<= 1) {
        int u = __shfl_up(t, off);
        if (lane >= off) t += u;
    }
    if (lane == 63) wsum[wave] = t;
    __syncthreads();
    int woff = 0;
    for (int w = 0; w < wave; w++) woff += wsum[w];
    int base = pscan[blockIdx.x] + woff + (t - s3);          // exclusive prefix
    if (i0 + 0 < N_NODES) rowptr[i0 + 0] = base;
    if (i0 + 1 < N_NODES) rowptr[i0 + 1] = base + s0;
    if (i0 + 2 < N_NODES) rowptr[i0 + 2] = base + s1;
    if (i0 + 3 < N_NODES) rowptr[i0 + 3] = base + s2;
}

// ---------------- fused: CSR scatter (mem-queue-bound) + layer1 GEMM (VALU-bound)
// scatter blocks first (longer), gemm1 blocks after; they overlap on the CUs.
__global__ __launch_bounds__(256) void k_scatter_gemm1(
    const int* __restrict__ e_src, const int* __restrict__ e_dst,
    const int* __restrict__ rowptr, int* __restrict__ cnt, int* __restrict__ csr_src,
    const float* __restrict__ x, const float* __restrict__ W1,
    const float* __restrict__ att_src1, const float* __restrict__ att_dst1,
    float* __restrict__ h1, float* __restrict__ a_src1, float* __restrict__ a_dst1) {
    __shared__ __align__(16) float wS[IN_F * C1];   // 32 KB, [k][col]
    __shared__ __align__(16) float xS[16 * 132];    // stride 132: aligned + conflict-free
    __shared__ float aSs[C1], aSd[C1];
    int tid = threadIdx.x;

    if (blockIdx.x < SCAT_NB) {                     // ---- scatter: 4 edges/thread
        int e0 = blockIdx.x * 1024 + tid;
#pragma unroll
        for (int j = 0; j < 4; j++) {
            int e = e0 + j * 256;
            if (e < N_EDGES) {
                int d = e_dst[e];
                int k = atomicAdd(&cnt[d], 1);
                csr_src[rowptr[d] + k] = e_src[e];
            }
        }
        return;
    }

    // ---- gemm1: 16 nodes/block; thread t: node_l=t>>4, cols (t&15)*4..+3
    int node0 = (blockIdx.x - SCAT_NB) * 16;
    for (int i = tid; i < (IN_F * C1) / 4; i += 256)
        *(float4*)&wS[i * 4] = *(const float4*)&W1[i * 4];
    for (int i = tid; i < (16 * IN_F) / 4; i += 256) {
        int r = i >> 5, c4 = (i & 31) << 2;          // 32 float4 per 128-wide row
        *(float4*)&xS[r * 132 + c4] = *(const float4*)&x[(node0 + r) * IN_F + c4];
    }
    if (tid < C1) { aSs[tid] = att_src1[tid]; aSd[tid] = att_dst1[tid]; }
    __syncthreads();

    int node_l = tid >> 4;
    int cq = (tid & 15) << 2;
    const float* xrow = &xS[node_l * 132];
    float4 acc = {0.f, 0.f, 0.f, 0.f};
#pragma unroll 4
    for (int k = 0; k < IN_F; k++) {
        float xv = xrow[k];
        float4 wv = *(const float4*)&wS[k * C1 + cq];
        acc.x += xv * wv.x; acc.y += xv * wv.y; acc.z += xv * wv.z; acc.w += xv * wv.w;
    }
    int node = node0 + node_l;
    *(float4*)&h1[node * C1 + cq] = acc;

    float ps = acc.x * aSs[cq] + acc.y * aSs[cq + 1] + acc.z * aSs[cq + 2] + acc.w * aSs[cq + 3];
    float pd = acc.x * aSd[cq] + acc.y * aSd[cq + 1] + acc.z * aSd[cq + 2] + acc.w * aSd[cq + 3];
    ps += __shfl_xor(ps, 1); ps += __shfl_xor(ps, 2);
    pd += __shfl_xor(pd, 1); pd += __shfl_xor(pd, 2);
    if ((tid & 3) == 0) {
        int h = (tid & 15) >> 2;
        a_src1[node * 4 + h] = ps;
        a_dst1[node * 4 + h] = pd;
    }
}

// ---------------- layer 1 segment-softmax + aggregate (one wave per node) ----
// no max pass (logits bounded, softmax shift-invariant); LDS-staged (src,w) pairs;
// serial loop unrolled x4 via ds_read_b128 pairs, 4 accumulator chains.
__global__ __launch_bounds__(256) void k_agg1(
    const float* __restrict__ h1, const float* __restrict__ a_src1,
    const float* __restrict__ a_dst1, const int* __restrict__ rowptr,
    const int* __restrict__ csr_src, const float* __restrict__ b1,
    float* __restrict__ out_emb) {
    __shared__ __align__(16) int2 swS[4][4][66];   // [wave][head][edge]; 66 -> 16B-aligned heads, disjoint banks
    int tid = threadIdx.x;
    int lane = tid & 63, wave = tid >> 6;
    int node = blockIdx.x * 4 + wave;
    int col = lane, h = lane >> 4;
    int rs = rowptr[node];
    int deg = rowptr[node + 1] - rs;

    float4 ad4 = *(const float4*)&a_dst1[node * 4];
    float4 as4 = *(const float4*)&a_src1[node * 4];
    float4 e04 = {lrelu(as4.x + ad4.x), lrelu(as4.y + ad4.y),
                  lrelu(as4.z + ad4.z), lrelu(as4.w + ad4.w)};
    float w0 = __expf(selh(e04, h));                // self-loop weight (no shift)
    float acc0 = w0 * h1[node * C1 + col];
    float acc1 = 0.f, acc2 = 0.f, acc3 = 0.f;
    float4 sac4 = {0.f, 0.f, 0.f, 0.f};            // lane-parallel denominator

    for (int base = 0; base < deg; base += 64) {
        int idx = base + lane;
        int s_l = 0;
        float4 w4 = {0.f, 0.f, 0.f, 0.f};
        if (idx < deg) {                            // lane-parallel weight compute
            s_l = csr_src[rs + idx];
            float4 as = *(const float4*)&a_src1[s_l * 4];
            w4.x = __expf(lrelu(as.x + ad4.x));
            w4.y = __expf(lrelu(as.y + ad4.y));
            w4.z = __expf(lrelu(as.z + ad4.z));
            w4.w = __expf(lrelu(as.w + ad4.w));
        }
        sac4.x += w4.x; sac4.y += w4.y; sac4.z += w4.z; sac4.w += w4.w;
        swS[wave][0][lane] = make_int2(s_l, __float_as_int(w4.x));
        swS[wave][1][lane] = make_int2(s_l, __float_as_int(w4.y));
        swS[wave][2][lane] = make_int2(s_l, __float_as_int(w4.z));
        swS[wave][3][lane] = make_int2(s_l, __float_as_int(w4.w));
        int nrem4 = (min(64, deg - base) + 3) & ~3; // pad slots carry w=0
        for (int j = 0; j < nrem4; j += 4) {        // 2x ds_read_b128, 4 chains
            int4 q0 = *(const int4*)&swS[wave][h][j];
            int4 q1 = *(const int4*)&swS[wave][h][j + 2];
            acc0 = fmaf(__int_as_float(q0.y), h1[q0.x * C1 + col], acc0);
            acc1 = fmaf(__int_as_float(q0.w), h1[q0.z * C1 + col], acc1);
            acc2 = fmaf(__int_as_float(q1.y), h1[q1.x * C1 + col], acc2);
            acc3 = fmaf(__int_as_float(q1.w), h1[q1.z * C1 + col], acc3);
        }
    }
    float acc = (acc0 + acc1) + (acc2 + acc3);
    for (int off = 32; off; off >>= 1) {            // reduce denominator (once)
        sac4.x += __shfl_xor(sac4.x, off);
        sac4.y += __shfl_xor(sac4.y, off);
        sac4.z += __shfl_xor(sac4.z, off);
        sac4.w += __shfl_xor(sac4.w, off);
    }
    float sacc = selh(sac4, h) + w0;

    float o = acc / sacc + b1[col];
    o = (o > 0.f) ? o : expm1f(o);                  // ELU
    out_emb[node * C1 + col] = o;                   // fp32 embeddings == h_act
}

// ---------------- layer 2 GEMM + attention dots ----------------
__global__ __launch_bounds__(256) void k_gemm2(
    const float* __restrict__ h_act, const float* __restrict__ W2,
    const float* __restrict__ att_src2, const float* __restrict__ att_dst2,
    float* __restrict__ h2, float* __restrict__ a_src2, float* __restrict__ a_dst2) {
    __shared__ float wS[C1 * NC];                 // 4 KB [k][c]
    __shared__ __align__(16) float hS[16 * 68];   // stride 68: aligned + conflict-free
    __shared__ float aS[NC], aD[NC];
    int tid = threadIdx.x;
    int node0 = blockIdx.x * 16;
    if (tid < (C1 * NC) / 4)
        *(float4*)&wS[tid * 4] = *(const float4*)&W2[tid * 4];
    {   // 16 rows x 64 cols of h_act, 256 float4s
        int r = tid >> 4, c4 = (tid & 15) << 2;
        *(float4*)&hS[r * 68 + c4] = *(const float4*)&h_act[(node0 + r) * C1 + c4];
    }
    if (tid < NC) { aS[tid] = att_src2[tid]; aD[tid] = att_dst2[tid]; }
    __syncthreads();

    int node_l = tid >> 4, c = tid & 15;
    const float* hr = &hS[node_l * 68];
    float acc = 0.f;
#pragma unroll 8
    for (int k = 0; k < C1; k++) acc += hr[k] * wS[k * NC + c];
    int node = node0 + node_l;
    h2[node * NC + c] = acc;

    float ps = acc * aS[c], pd = acc * aD[c];
    for (int off = 8; off; off >>= 1) { ps += __shfl_xor(ps, off); pd += __shfl_xor(pd, off); }
    if (c == 0) { a_src2[node] = ps; a_dst2[node] = pd; }
}

// ---------------- layer 2 softmax-aggregate + log_softmax (no max pass) -----
__global__ __launch_bounds__(256) void k_agg2(
    const float* __restrict__ h2, const float* __restrict__ a_src2,
    const float* __restrict__ a_dst2, const int* __restrict__ rowptr,
    const int* __restrict__ csr_src, const float* __restrict__ b2,
    float* __restrict__ out_lsm) {
    __shared__ int2 swS[4][64];                     // [wave][edge] = (src, w)
    int tid = threadIdx.x;
    int lane = tid & 63, wave = tid >> 6;
    int node = blockIdx.x * 4 + wave;
    int esub = lane >> 4, c = lane & 15;
    int rs = rowptr[node];
    int deg = rowptr[node + 1] - rs;

    float adst = a_dst2[node];
    float w0 = __expf(lrelu(a_src2[node] + adst));
    float sacc_l = 0.f;                             // lane-parallel denominator
    float accA = (esub == 0) ? w0 * h2[node * NC + c] : 0.f;
    float accB = 0.f;

    for (int base = 0; base < deg; base += 64) {
        int idx = base + lane;
        int s_l = 0; float w_l = 0.f;
        if (idx < deg) {                            // lane-parallel weight compute
            s_l = csr_src[rs + idx];
            w_l = __expf(lrelu(a_src2[s_l] + adst));
        }
        sacc_l += w_l;
        swS[wave][lane] = make_int2(s_l, __float_as_int(w_l));
        int nrem8 = (min(64, deg - base) + 7) & ~7; // pad slots carry w=0
        for (int j2 = 0; j2 < nrem8; j2 += 8) {     // 2 pairs x (4 edges x 16 cols)
            int2 p0 = swS[wave][j2 + esub];
            int2 p1 = swS[wave][j2 + 4 + esub];
            accA = fmaf(__int_as_float(p0.y), h2[p0.x * NC + c], accA);
            accB = fmaf(__int_as_float(p1.y), h2[p1.x * NC + c], accB);
        }
    }
    float acc = accA + accB;
    acc += __shfl_xor(acc, 16); acc += __shfl_xor(acc, 32);
    for (int off = 32; off; off >>= 1) sacc_l += __shfl_xor(sacc_l, off);
    float sacc = sacc_l + w0;

    float logit = acc / sacc + b2[c];
    float mxl = logit;
    for (int off = 8; off; off >>= 1) mxl = fmaxf(mxl, __shfl_xor(mxl, off));
    float ex = __expf(logit - mxl);
    float se = ex;
    for (int off = 8; off; off >>= 1) se += __shfl_xor(se, off);
    float lsm = (logit - mxl) - __logf(se);
    if (esub == 0) out_lsm[node * NC + c] = lsm;
}

extern "C" void kernel_launch(void* const* d_in, const int* in_sizes, int n_in,
                              void* d_out, int out_size, void* d_ws, size_t ws_size,
                              hipStream_t stream) {
    const float* x   = (const float*)d_in[0];
    const int* ei    = (const int*)d_in[1];   // [2,E]: src row then dst row
    const float* W1  = (const float*)d_in[2];
    const float* as1 = (const float*)d_in[3];
    const float* ad1 = (const float*)d_in[4];
    const float* b1  = (const float*)d_in[5];
    const float* W2  = (const float*)d_in[6];
    const float* as2 = (const float*)d_in[7];
    const float* ad2 = (const float*)d_in[8];
    const float* b2  = (const float*)d_in[9];
    float* out = (float*)d_out;               // [N*16 log_softmax][N*64 embeddings]
    float* out_lsm = out;
    float* out_emb = out + (size_t)N_NODES * NC;

    float* ws = (float*)d_ws;
    float* h1     = ws;                              // N*64
    float* a_src1 = h1     + (size_t)N_NODES * C1;   // N*4
    float* a_dst1 = a_src1 + (size_t)N_NODES * 4;    // N*4
    float* h2     = a_dst1 + (size_t)N_NODES * 4;    // N*16
    float* a_src2 = h2     + (size_t)N_NODES * NC;   // N
    float* a_dst2 = a_src2 + (size_t)N_NODES;        // N
    int*   deg    = (int*)(a_dst2 + N_NODES);        // N
    int*   cnt    = deg + N_NODES;                   // N
    int*   rowptr = cnt + N_NODES;                   // N+1
    int*   csr    = rowptr + N_NODES + 1;            // E
    int*   partial= csr + N_EDGES;                   // SCAN_NB
    int*   pscan  = partial + SCAN_NB;               // SCAN_NB

    const int* e_src = ei;
    const int* e_dst = ei + N_EDGES;

    hipMemsetAsync(deg, 0, 2 * (size_t)N_NODES * sizeof(int), stream);  // deg + cnt
    k_hist <<<N_EDGES / 256, 256, 0, stream>>>(e_dst, deg);
    k_scan1<<<SCAN_NB, 256, 0, stream>>>(deg, partial);
    k_scan2<<<1, 128, 0, stream>>>(partial, pscan, rowptr);
    k_scan3<<<SCAN_NB, 256, 0, stream>>>(deg, pscan, rowptr);

    k_scatter_gemm1<<<SCAT_NB + GEMM1_NB, 256, 0, stream>>>(
        e_src, e_dst, rowptr, cnt, csr, x, W1, as1, ad1, h1, a_src1, a_dst1);

    k_agg1 <<<N_NODES / 4, 256, 0, stream>>>(h1, a_src1, a_dst1, rowptr, csr, b1, out_emb);
    k_gemm2<<<N_NODES / 16, 256, 0, stream>>>(out_emb, W2, as2, ad2, h2, a_src2, a_dst2);
    k_agg2 <<<N_NODES / 4, 256, 0, stream>>>(h2, a_src2, a_dst2, rowptr, csr, b2, out_lsm);
}

// Round 6
// 400.717 us; speedup vs baseline: 1.7323x; 1.1226x over previous
//
#include <hip/hip_runtime.h>
#include <hip/hip_bf16.h>

#define N_NODES 100000
#define N_EDGES 1600000
#define IN_F 128
#define C1 64      // HEADS*HID
#define NC 16      // classes / layer2 width

#define SCAN_TILE 1024
#define SCAN_NB ((N_NODES + SCAN_TILE - 1) / SCAN_TILE)   // 98 blocks
#define GEMM1_NB (N_NODES / 16)                           // 6250
#define HIST_NB ((N_EDGES + 1023) / 1024)                 // 1563 (4 edges/thread)

__device__ __forceinline__ float lrelu(float x) { return fmaxf(x, 0.2f * x); }
__device__ __forceinline__ float selh(float4 v, int h) {
    return (h == 0) ? v.x : (h == 1) ? v.y : (h == 2) ? v.z : v.w;
}

// ---------------- fused: histogram+rank (mem-latency-bound) + layer1 GEMM ----
// hist blocks first; gemm1 blocks after. Two-stage W staging keeps LDS at
// ~25KB -> 6 blocks/CU so the hist blocks keep high occupancy.
__global__ __launch_bounds__(256) void k_hist_gemm1(
    const int* __restrict__ e_dst, int* __restrict__ deg, int* __restrict__ rank,
    const float* __restrict__ x, const float* __restrict__ W1,
    const float* __restrict__ att_src1, const float* __restrict__ att_dst1,
    float* __restrict__ h1, float* __restrict__ a_src1, float* __restrict__ a_dst1) {
    __shared__ __align__(16) float wS[64 * C1];     // 16 KB, one k-half of W1
    __shared__ __align__(16) float xS[16 * 132];    // stride 132: aligned + conflict-free
    __shared__ float aSs[C1], aSd[C1];
    int tid = threadIdx.x;

    if (blockIdx.x < HIST_NB) {                     // ---- hist + rank: 4 edges/thread
        int e0 = blockIdx.x * 1024 + tid;
#pragma unroll
        for (int j = 0; j < 4; j++) {
            int e = e0 + j * 256;
            if (e < N_EDGES) {
                int d = e_dst[e];
                rank[e] = atomicAdd(&deg[d], 1);    // rank within dst bucket
            }
        }
        return;
    }

    // ---- gemm1: 16 nodes/block; thread t: node_l=t>>4, cols (t&15)*4..+3
    int node0 = (blockIdx.x - HIST_NB) * 16;
    for (int i = tid; i < (16 * IN_F) / 4; i += 256) {
        int r = i >> 5, c4 = (i & 31) << 2;          // 32 float4 per 128-wide row
        *(float4*)&xS[r * 132 + c4] = *(const float4*)&x[(node0 + r) * IN_F + c4];
    }
    if (tid < C1) { aSs[tid] = att_src1[tid]; aSd[tid] = att_dst1[tid]; }

    int node_l = tid >> 4;
    int cq = (tid & 15) << 2;
    const float* xrow = &xS[node_l * 132];
    float4 acc = {0.f, 0.f, 0.f, 0.f};
#pragma unroll
    for (int kt = 0; kt < 2; kt++) {                // two 64-wide k-tiles of W1
        __syncthreads();                            // protect wS reuse
        for (int i = tid; i < (64 * C1) / 4; i += 256)
            *(float4*)&wS[i * 4] = *(const float4*)&W1[kt * 64 * C1 + i * 4];
        __syncthreads();
        const float* xk = xrow + kt * 64;
#pragma unroll 4
        for (int k = 0; k < 64; k++) {
            float xv = xk[k];
            float4 wv = *(const float4*)&wS[k * C1 + cq];
            acc.x += xv * wv.x; acc.y += xv * wv.y; acc.z += xv * wv.z; acc.w += xv * wv.w;
        }
    }
    int node = node0 + node_l;
    *(float4*)&h1[node * C1 + cq] = acc;

    float ps = acc.x * aSs[cq] + acc.y * aSs[cq + 1] + acc.z * aSs[cq + 2] + acc.w * aSs[cq + 3];
    float pd = acc.x * aSd[cq] + acc.y * aSd[cq + 1] + acc.z * aSd[cq + 2] + acc.w * aSd[cq + 3];
    ps += __shfl_xor(ps, 1); ps += __shfl_xor(ps, 2);
    pd += __shfl_xor(pd, 1); pd += __shfl_xor(pd, 2);
    if ((tid & 3) == 0) {
        int h = (tid & 15) >> 2;
        a_src1[node * 4 + h] = ps;
        a_dst1[node * 4 + h] = pd;
    }
}

// pass 1: per-block sums of deg (1024 elems per 256-thread block)
__global__ __launch_bounds__(256) void k_scan1(const int* __restrict__ deg,
                                               int* __restrict__ partial) {
    __shared__ int wsum[4];
    int tid = threadIdx.x;
    int i0 = blockIdx.x * SCAN_TILE + tid * 4;
    int s = 0;
#pragma unroll
    for (int j = 0; j < 4; j++) { int i = i0 + j; if (i < N_NODES) s += deg[i]; }
    for (int off = 32; off; off >>= 1) s += __shfl_xor(s, off);
    if ((tid & 63) == 0) wsum[tid >> 6] = s;
    __syncthreads();
    if (tid == 0) partial[blockIdx.x] = wsum[0] + wsum[1] + wsum[2] + wsum[3];
}

// pass 2: exclusive scan of the 98 partials (single tiny block)
__global__ void k_scan2(const int* __restrict__ partial, int* __restrict__ pscan,
                        int* __restrict__ rowptr) {
    __shared__ int buf[128];
    int tid = threadIdx.x;
    int v = (tid < SCAN_NB) ? partial[tid] : 0;
    buf[tid] = v;
    __syncthreads();
    for (int d = 1; d < 128; d <<= 1) {
        int t = (tid >= d) ? buf[tid - d] : 0;
        __syncthreads();
        buf[tid] += t;
        __syncthreads();
    }
    if (tid < SCAN_NB) pscan[tid] = buf[tid] - v;    // exclusive
    if (tid == 0) rowptr[N_NODES] = N_EDGES;         // total is static
}

// pass 3: block-local exclusive scan + block offset -> rowptr
__global__ __launch_bounds__(256) void k_scan3(const int* __restrict__ deg,
                                               const int* __restrict__ pscan,
                                               int* __restrict__ rowptr) {
    __shared__ int wsum[4];
    int tid = threadIdx.x, lane = tid & 63, wave = tid >> 6;
    int i0 = blockIdx.x * SCAN_TILE + tid * 4;
    int v0 = 0, v1 = 0, v2 = 0, v3 = 0;
    if (i0 + 0 < N_NODES) v0 = deg[i0 + 0];
    if (i0 + 1 < N_NODES) v1 = deg[i0 + 1];
    if (i0 + 2 < N_NODES) v2 = deg[i0 + 2];
    if (i0 + 3 < N_NODES) v3 = deg[i0 + 3];
    int s0 = v0, s1 = s0 + v1, s2 = s1 + v2, s3 = s2 + v3;   // thread-local inclusive
    int t = s3;                                              // wave inclusive scan
    for (int off = 1; off < 64; off <<= 1) {
        int u = __shfl_up(t, off);
        if (lane >= off) t += u;
    }
    if (lane == 63) wsum[wave] = t;
    __syncthreads();
    int woff = 0;
    for (int w = 0; w < wave; w++) woff += wsum[w];
    int base = pscan[blockIdx.x] + woff + (t - s3);          // exclusive prefix
    if (i0 + 0 < N_NODES) rowptr[i0 + 0] = base;
    if (i0 + 1 < N_NODES) rowptr[i0 + 1] = base + s0;
    if (i0 + 2 < N_NODES) rowptr[i0 + 2] = base + s1;
    if (i0 + 3 < N_NODES) rowptr[i0 + 3] = base + s2;
}

// atomic-free scatter: rank was captured during hist
__global__ __launch_bounds__(256) void k_scatter(
    const int* __restrict__ e_src, const int* __restrict__ e_dst,
    const int* __restrict__ rank, const int* __restrict__ rowptr,
    int* __restrict__ csr_src) {
    int e0 = blockIdx.x * 1024 + threadIdx.x;
#pragma unroll
    for (int j = 0; j < 4; j++) {
        int e = e0 + j * 256;
        if (e < N_EDGES)
            csr_src[rowptr[e_dst[e]] + rank[e]] = e_src[e];
    }
}

// ---------------- layer 1 segment-softmax + aggregate (one wave per node) ----
// no max pass (logits bounded, softmax shift-invariant); LDS-staged (src,w) pairs;
// serial loop unrolled x4 via ds_read_b128 pairs, 4 accumulator chains.
__global__ __launch_bounds__(256) void k_agg1(
    const float* __restrict__ h1, const float* __restrict__ a_src1,
    const float* __restrict__ a_dst1, const int* __restrict__ rowptr,
    const int* __restrict__ csr_src, const float* __restrict__ b1,
    float* __restrict__ out_emb) {
    __shared__ __align__(16) int2 swS[4][4][66];   // [wave][head][edge]; 66 -> 16B-aligned heads
    int tid = threadIdx.x;
    int lane = tid & 63, wave = tid >> 6;
    int node = blockIdx.x * 4 + wave;
    int col = lane, h = lane >> 4;
    int rs = rowptr[node];
    int deg = rowptr[node + 1] - rs;

    float4 ad4 = *(const float4*)&a_dst1[node * 4];
    float4 as4 = *(const float4*)&a_src1[node * 4];
    float4 e04 = {lrelu(as4.x + ad4.x), lrelu(as4.y + ad4.y),
                  lrelu(as4.z + ad4.z), lrelu(as4.w + ad4.w)};
    float w0 = __expf(selh(e04, h));                // self-loop weight (no shift)
    float acc0 = w0 * h1[node * C1 + col];
    float acc1 = 0.f, acc2 = 0.f, acc3 = 0.f;
    float4 sac4 = {0.f, 0.f, 0.f, 0.f};            // lane-parallel denominator

    for (int base = 0; base < deg; base += 64) {
        int idx = base + lane;
        int s_l = 0;
        float4 w4 = {0.f, 0.f, 0.f, 0.f};
        if (idx < deg) {                            // lane-parallel weight compute
            s_l = csr_src[rs + idx];
            float4 as = *(const float4*)&a_src1[s_l * 4];
            w4.x = __expf(lrelu(as.x + ad4.x));
            w4.y = __expf(lrelu(as.y + ad4.y));
            w4.z = __expf(lrelu(as.z + ad4.z));
            w4.w = __expf(lrelu(as.w + ad4.w));
        }
        sac4.x += w4.x; sac4.y += w4.y; sac4.z += w4.z; sac4.w += w4.w;
        swS[wave][0][lane] = make_int2(s_l, __float_as_int(w4.x));
        swS[wave][1][lane] = make_int2(s_l, __float_as_int(w4.y));
        swS[wave][2][lane] = make_int2(s_l, __float_as_int(w4.z));
        swS[wave][3][lane] = make_int2(s_l, __float_as_int(w4.w));
        int nrem4 = (min(64, deg - base) + 3) & ~3; // pad slots carry w=0
        for (int j = 0; j < nrem4; j += 4) {        // 2x ds_read_b128, 4 chains
            int4 q0 = *(const int4*)&swS[wave][h][j];
            int4 q1 = *(const int4*)&swS[wave][h][j + 2];
            acc0 = fmaf(__int_as_float(q0.y), h1[q0.x * C1 + col], acc0);
            acc1 = fmaf(__int_as_float(q0.w), h1[q0.z * C1 + col], acc1);
            acc2 = fmaf(__int_as_float(q1.y), h1[q1.x * C1 + col], acc2);
            acc3 = fmaf(__int_as_float(q1.w), h1[q1.z * C1 + col], acc3);
        }
    }
    float acc = (acc0 + acc1) + (acc2 + acc3);
    for (int off = 32; off; off >>= 1) {            // reduce denominator (once)
        sac4.x += __shfl_xor(sac4.x, off);
        sac4.y += __shfl_xor(sac4.y, off);
        sac4.z += __shfl_xor(sac4.z, off);
        sac4.w += __shfl_xor(sac4.w, off);
    }
    float sacc = selh(sac4, h) + w0;

    float o = acc / sacc + b1[col];
    o = (o > 0.f) ? o : expm1f(o);                  // ELU
    out_emb[node * C1 + col] = o;                   // fp32 embeddings == h_act
}

// ---------------- layer 2 GEMM + attention dots ----------------
__global__ __launch_bounds__(256) void k_gemm2(
    const float* __restrict__ h_act, const float* __restrict__ W2,
    const float* __restrict__ att_src2, const float* __restrict__ att_dst2,
    float* __restrict__ h2, float* __restrict__ a_src2, float* __restrict__ a_dst2) {
    __shared__ float wS[C1 * NC];                 // 4 KB [k][c]
    __shared__ __align__(16) float hS[16 * 68];   // stride 68: aligned + conflict-free
    __shared__ float aS[NC], aD[NC];
    int tid = threadIdx.x;
    int node0 = blockIdx.x * 16;
    if (tid < (C1 * NC) / 4)
        *(float4*)&wS[tid * 4] = *(const float4*)&W2[tid * 4];
    {   // 16 rows x 64 cols of h_act, 256 float4s
        int r = tid >> 4, c4 = (tid & 15) << 2;
        *(float4*)&hS[r * 68 + c4] = *(const float4*)&h_act[(node0 + r) * C1 + c4];
    }
    if (tid < NC) { aS[tid] = att_src2[tid]; aD[tid] = att_dst2[tid]; }
    __syncthreads();

    int node_l = tid >> 4, c = tid & 15;
    const float* hr = &hS[node_l * 68];
    float acc = 0.f;
#pragma unroll 8
    for (int k = 0; k < C1; k++) acc += hr[k] * wS[k * NC + c];
    int node = node0 + node_l;
    h2[node * NC + c] = acc;

    float ps = acc * aS[c], pd = acc * aD[c];
    for (int off = 8; off; off >>= 1) { ps += __shfl_xor(ps, off); pd += __shfl_xor(pd, off); }
    if (c == 0) { a_src2[node] = ps; a_dst2[node] = pd; }
}

// ---------------- layer 2 softmax-aggregate + log_softmax (no max pass) -----
__global__ __launch_bounds__(256) void k_agg2(
    const float* __restrict__ h2, const float* __restrict__ a_src2,
    const float* __restrict__ a_dst2, const int* __restrict__ rowptr,
    const int* __restrict__ csr_src, const float* __restrict__ b2,
    float* __restrict__ out_lsm) {
    __shared__ int2 swS[4][64];                     // [wave][edge] = (src, w)
    int tid = threadIdx.x;
    int lane = tid & 63, wave = tid >> 6;
    int node = blockIdx.x * 4 + wave;
    int esub = lane >> 4, c = lane & 15;
    int rs = rowptr[node];
    int deg = rowptr[node + 1] - rs;

    float adst = a_dst2[node];
    float w0 = __expf(lrelu(a_src2[node] + adst));
    float sacc_l = 0.f;                             // lane-parallel denominator
    float accA = (esub == 0) ? w0 * h2[node * NC + c] : 0.f;
    float accB = 0.f;

    for (int base = 0; base < deg; base += 64) {
        int idx = base + lane;
        int s_l = 0; float w_l = 0.f;
        if (idx < deg) {                            // lane-parallel weight compute
            s_l = csr_src[rs + idx];
            w_l = __expf(lrelu(a_src2[s_l] + adst));
        }
        sacc_l += w_l;
        swS[wave][lane] = make_int2(s_l, __float_as_int(w_l));
        int nrem8 = (min(64, deg - base) + 7) & ~7; // pad slots carry w=0
        for (int j2 = 0; j2 < nrem8; j2 += 8) {     // 2 pairs x (4 edges x 16 cols)
            int2 p0 = swS[wave][j2 + esub];
            int2 p1 = swS[wave][j2 + 4 + esub];
            accA = fmaf(__int_as_float(p0.y), h2[p0.x * NC + c], accA);
            accB = fmaf(__int_as_float(p1.y), h2[p1.x * NC + c], accB);
        }
    }
    float acc = accA + accB;
    acc += __shfl_xor(acc, 16); acc += __shfl_xor(acc, 32);
    for (int off = 32; off; off >>= 1) sacc_l += __shfl_xor(sacc_l, off);
    float sacc = sacc_l + w0;

    float logit = acc / sacc + b2[c];
    float mxl = logit;
    for (int off = 8; off; off >>= 1) mxl = fmaxf(mxl, __shfl_xor(mxl, off));
    float ex = __expf(logit - mxl);
    float se = ex;
    for (int off = 8; off; off >>= 1) se += __shfl_xor(se, off);
    float lsm = (logit - mxl) - __logf(se);
    if (esub == 0) out_lsm[node * NC + c] = lsm;
}

extern "C" void kernel_launch(void* const* d_in, const int* in_sizes, int n_in,
                              void* d_out, int out_size, void* d_ws, size_t ws_size,
                              hipStream_t stream) {
    const float* x   = (const float*)d_in[0];
    const int* ei    = (const int*)d_in[1];   // [2,E]: src row then dst row
    const float* W1  = (const float*)d_in[2];
    const float* as1 = (const float*)d_in[3];
    const float* ad1 = (const float*)d_in[4];
    const float* b1  = (const float*)d_in[5];
    const float* W2  = (const float*)d_in[6];
    const float* as2 = (const float*)d_in[7];
    const float* ad2 = (const float*)d_in[8];
    const float* b2  = (const float*)d_in[9];
    float* out = (float*)d_out;               // [N*16 log_softmax][N*64 embeddings]
    float* out_lsm = out;
    float* out_emb = out + (size_t)N_NODES * NC;

    float* ws = (float*)d_ws;
    float* h1     = ws;                              // N*64
    float* a_src1 = h1     + (size_t)N_NODES * C1;   // N*4
    float* a_dst1 = a_src1 + (size_t)N_NODES * 4;    // N*4
    float* h2     = a_dst1 + (size_t)N_NODES * 4;    // N*16
    float* a_src2 = h2     + (size_t)N_NODES * NC;   // N
    float* a_dst2 = a_src2 + (size_t)N_NODES;        // N
    int*   deg    = (int*)(a_dst2 + N_NODES);        // N
    int*   rowptr = deg + N_NODES;                   // N+1
    int*   csr    = rowptr + N_NODES + 1;            // E
    int*   rank   = csr + N_EDGES;                   // E
    int*   partial= rank + N_EDGES;                  // SCAN_NB
    int*   pscan  = partial + SCAN_NB;               // SCAN_NB

    const int* e_src = ei;
    const int* e_dst = ei + N_EDGES;

    hipMemsetAsync(deg, 0, (size_t)N_NODES * sizeof(int), stream);

    k_hist_gemm1<<<HIST_NB + GEMM1_NB, 256, 0, stream>>>(
        e_dst, deg, rank, x, W1, as1, ad1, h1, a_src1, a_dst1);

    k_scan1<<<SCAN_NB, 256, 0, stream>>>(deg, partial);
    k_scan2<<<1, 128, 0, stream>>>(partial, pscan, rowptr);
    k_scan3<<<SCAN_NB, 256, 0, stream>>>(deg, pscan, rowptr);

    k_scatter<<<HIST_NB, 256, 0, stream>>>(e_src, e_dst, rank, rowptr, csr);

    k_agg1 <<<N_NODES / 4, 256, 0, stream>>>(h1, a_src1, a_dst1, rowptr, csr, b1, out_emb);
    k_gemm2<<<N_NODES / 16, 256, 0, stream>>>(out_emb, W2, as2, ad2, h2, a_src2, a_dst2);
    k_agg2 <<<N_NODES / 4, 256, 0, stream>>>(h2, a_src2, a_dst2, rowptr, csr, b2, out_lsm);
}